// Round 17
// baseline (59.086 us; speedup 1.0000x reference)
//
#include <hip/hip_runtime.h>

#define K_OFF 27
#define CIN   2
#define COUT  16
#define BLK   256
#define WPB   4
#define IPW   (64 * K_OFF)      // 1728 ints per wave tile
#define NB    12                // one deep asm-clustered batch covers mx<=12 (~all tiles)

typedef __attribute__((address_space(3))) unsigned int lds_u32;
typedef __attribute__((address_space(1))) const unsigned int g_u32;

// ---- prologue: pack fp32 feats [N][2] -> bf16x2 u32 [N] (RTNE) ----
__global__ __launch_bounds__(256) void pack_feats_kernel(
    const float2* __restrict__ feats2, unsigned* __restrict__ pkf, int n)
{
    const int i = blockIdx.x * 256 + threadIdx.x;
    if (i < n) {
        const float2 f = feats2[i];
        unsigned bx = __float_as_uint(f.x);
        unsigned by = __float_as_uint(f.y);
        bx = (bx + 0x7FFFu + ((bx >> 16) & 1u)) >> 16;
        by = (by + 0x7FFFu + ((by >> 16) & 1u)) >> 16;
        pkf[i] = bx | (by << 16);
    }
}

__global__ __launch_bounds__(BLK, 4) void spconv_kernel(
    const unsigned* __restrict__ pkf,  // [N] bf16x2 (4 MB, L2-resident)
    const float* __restrict__ w,       // [27][2][16]
    const int*   __restrict__ nbr,     // [N][27]
    float*       __restrict__ out,     // [N][16]
    int n_pts)
{
    __shared__ int    s_idx[WPB * IPW];   // 27648 B single-buffer -> 5 blocks/CU
    __shared__ float4 s_w[8 * K_OFF];     // 3456 B

    const int t    = threadIdx.x;
    const int lane = t & 63;
    const int wv   = t >> 6;
    const int tile = blockIdx.x * WPB + wv;
    const int p    = tile * 64 + lane;

    if (t < 8 * K_OFF) {                  // W -> LDS, [q][k] layout
        const int k = t >> 3, q = t & 7;
        s_w[q * K_OFF + k] = reinterpret_cast<const float4*>(w)[t];
    }

    const bool full = ((tile + 1) * 64 <= n_pts);   // wave-uniform
    if (full) {
        const int* src = nbr + (size_t)tile * IPW;
        int*       dst = s_idx + wv * IPW;
        #pragma unroll
        for (int j = 0; j < 6; ++j)
            __builtin_amdgcn_global_load_lds((g_u32*)(src + j * 256 + lane * 4),
                                             (lds_u32*)(dst + j * 256), 16, 0, 0);
        if (lane < 48)
            __builtin_amdgcn_global_load_lds((g_u32*)(src + 6 * 256 + lane * 4),
                                             (lds_u32*)(dst + 6 * 256), 16, 0, 0);
    }
    __syncthreads();   // compiler-emitted vmcnt(0)+lgkmcnt(0): stage & W retired here

    float acc[COUT];
    #pragma unroll
    for (int d = 0; d < COUT; ++d) acc[d] = 0.f;

    const int* rowp = s_idx + wv * IPW + lane * K_OFF;

    unsigned bm = 0;
    if (full) {
        #pragma unroll
        for (int k = 0; k < K_OFF; ++k)
            bm |= (rowp[k] >= 0) ? (1u << k) : 0u;
    }
    const int nv = __popc(bm);            // this lane's valid count
    int mx = nv;
    #pragma unroll
    for (int off = 32; off; off >>= 1) mx = max(mx, __shfl_xor(mx, off, 64));

    if (full) {
        // ---- one deep batch: NB=12 asm-clustered dword gathers, all in flight ----
        int kk[NB]; unsigned u[NB];
        #pragma unroll
        for (int j = 0; j < NB; ++j) {
            kk[j] = (bm != 0) ? (int)__builtin_ctz(bm) : 0;
            bm &= bm - 1;
        }
        #pragma unroll
        for (int j = 0; j < NB; ++j) {
            const int idx = rowp[kk[j]];
            const unsigned* ap = pkf + ((j < nv && idx > 0) ? idx : 0);
            asm volatile("global_load_dword %0, %1, off" : "=v"(u[j]) : "v"(ap));
        }
        asm volatile("s_waitcnt vmcnt(0)" ::: "memory");
        __builtin_amdgcn_sched_barrier(0);   // keep FMAs below the wait

        #pragma unroll
        for (int j = 0; j < NB; ++j) {
            const float fm = (j < nv) ? 1.0f : 0.0f;
            const float fx = __uint_as_float(u[j] << 16) * fm;
            const float fy = __uint_as_float(u[j] & 0xFFFF0000u) * fm;
            const int k = kk[j];
            #pragma unroll
            for (int q = 0; q < 4; ++q) {
                const float4 wa = s_w[q * K_OFF + k];
                const float4 wb = s_w[(q + 4) * K_OFF + k];
                acc[q*4+0] = fmaf(fy, wb.x, fmaf(fx, wa.x, acc[q*4+0]));
                acc[q*4+1] = fmaf(fy, wb.y, fmaf(fx, wa.y, acc[q*4+1]));
                acc[q*4+2] = fmaf(fy, wb.z, fmaf(fx, wa.z, acc[q*4+2]));
                acc[q*4+3] = fmaf(fy, wb.w, fmaf(fx, wa.w, acc[q*4+3]));
            }
        }

        // ---- overflow batches (mx > 12): ~never taken at this density ----
        for (int j0 = NB; j0 < mx; j0 += NB) {
            int kx[NB]; unsigned ux[NB];
            #pragma unroll
            for (int j = 0; j < NB; ++j) {
                kx[j] = (bm != 0) ? (int)__builtin_ctz(bm) : 0;
                bm &= bm - 1;
            }
            #pragma unroll
            for (int j = 0; j < NB; ++j) {
                const int idx = rowp[kx[j]];
                const unsigned* ap = pkf + ((j0 + j < nv && idx > 0) ? idx : 0);
                asm volatile("global_load_dword %0, %1, off" : "=v"(ux[j]) : "v"(ap));
            }
            asm volatile("s_waitcnt vmcnt(0)" ::: "memory");
            __builtin_amdgcn_sched_barrier(0);
            #pragma unroll
            for (int j = 0; j < NB; ++j) {
                const float fm = (j0 + j < nv) ? 1.0f : 0.0f;
                const float fx = __uint_as_float(ux[j] << 16) * fm;
                const float fy = __uint_as_float(ux[j] & 0xFFFF0000u) * fm;
                const int k = kx[j];
                #pragma unroll
                for (int q = 0; q < 4; ++q) {
                    const float4 wa = s_w[q * K_OFF + k];
                    const float4 wb = s_w[(q + 4) * K_OFF + k];
                    acc[q*4+0] = fmaf(fy, wb.x, fmaf(fx, wa.x, acc[q*4+0]));
                    acc[q*4+1] = fmaf(fy, wb.y, fmaf(fx, wa.y, acc[q*4+1]));
                    acc[q*4+2] = fmaf(fy, wb.z, fmaf(fx, wa.z, acc[q*4+2]));
                    acc[q*4+3] = fmaf(fy, wb.w, fmaf(fx, wa.w, acc[q*4+3]));
                }
            }
        }
    } else {
        // partial tile (none for n%64==0): dense masked, direct reads
        const bool pv = (p < n_pts);
        for (int k = 0; k < K_OFF; ++k) {
            const int idx = pv ? nbr[(size_t)p * K_OFF + k] : -1;
            const float fm = (idx >= 0) ? 1.0f : 0.0f;
            const unsigned uu = pkf[idx > 0 ? idx : 0];
            const float fx = __uint_as_float(uu << 16) * fm;
            const float fy = __uint_as_float(uu & 0xFFFF0000u) * fm;
            #pragma unroll
            for (int q = 0; q < 4; ++q) {
                const float4 wa = s_w[q * K_OFF + k];
                const float4 wb = s_w[(q + 4) * K_OFF + k];
                acc[q*4+0] = fmaf(fy, wb.x, fmaf(fx, wa.x, acc[q*4+0]));
                acc[q*4+1] = fmaf(fy, wb.y, fmaf(fx, wa.y, acc[q*4+1]));
                acc[q*4+2] = fmaf(fy, wb.z, fmaf(fx, wa.z, acc[q*4+2]));
                acc[q*4+3] = fmaf(fy, wb.w, fmaf(fx, wa.w, acc[q*4+3]));
            }
        }
    }

    if (p < n_pts) {
        float4* o = reinterpret_cast<float4*>(out + (size_t)p * COUT);
        o[0] = make_float4(acc[0],  acc[1],  acc[2],  acc[3]);
        o[1] = make_float4(acc[4],  acc[5],  acc[6],  acc[7]);
        o[2] = make_float4(acc[8],  acc[9],  acc[10], acc[11]);
        o[3] = make_float4(acc[12], acc[13], acc[14], acc[15]);
    }
}

extern "C" void kernel_launch(void* const* d_in, const int* in_sizes, int n_in,
                              void* d_out, int out_size, void* d_ws, size_t ws_size,
                              hipStream_t stream) {
    const float* feats = (const float*)d_in[0];
    const float* w     = (const float*)d_in[1];
    const int*   nbr   = (const int*)d_in[2];
    float*       out   = (float*)d_out;
    unsigned*    pkf   = (unsigned*)d_ws;          // 4 MB packed bf16 feats

    const int n_pts   = in_sizes[0] / CIN;
    const int n_tiles = (n_pts + 63) / 64;
    const int grid    = (n_tiles + WPB - 1) / WPB;

    pack_feats_kernel<<<(n_pts + 255) / 256, 256, 0, stream>>>(
        reinterpret_cast<const float2*>(feats), pkf, n_pts);
    spconv_kernel<<<grid, BLK, 0, stream>>>(pkf, w, nbr, out, n_pts);
}

// Round 18
// 53.593 us; speedup vs baseline: 1.1025x; 1.1025x over previous
//
#include <hip/hip_runtime.h>

#define K_OFF 27
#define CIN   2
#define COUT  16
#define BLK   256
#define WPB   4                 // waves per block
#define IPW   (64 * K_OFF)      // 1728 ints per wave tile
#define NB    8                 // batch width: 8 gathers in flight (asm-enforced)

typedef __attribute__((address_space(3))) unsigned int lds_u32;
typedef __attribute__((address_space(1))) const unsigned int g_u32;

__global__ __launch_bounds__(BLK, 2) void spconv_kernel(
    const float* __restrict__ feats,   // [N][2]
    const float* __restrict__ w,       // [27][2][16]
    const int*   __restrict__ nbr,     // [N][27]
    float*       __restrict__ out,     // [N][16]
    int n_pts)
{
    __shared__ int    s_idx[WPB * IPW];   // 27648 B, wave-private staging
    __shared__ float4 s_w[8 * K_OFF];     // 3456 B, W as [q][k] float4

    const int t    = threadIdx.x;
    const int lane = t & 63;
    const int wv   = t >> 6;
    const int tile = blockIdx.x * WPB + wv;
    const int p    = tile * 64 + lane;

    // ---- W -> LDS, [q][k] layout ----
    if (t < 8 * K_OFF) {
        const int k = t >> 3, q = t & 7;
        s_w[q * K_OFF + k] = reinterpret_cast<const float4*>(w)[t];
    }

    const bool full = ((tile + 1) * 64 <= n_pts);   // wave-uniform
    if (full) {
        const int* src = nbr + (size_t)tile * IPW;
        int*       dst = s_idx + wv * IPW;
        #pragma unroll
        for (int j = 0; j < 6; ++j) {
            __builtin_amdgcn_global_load_lds(
                (g_u32*)(src + j * 256 + lane * 4),
                (lds_u32*)(dst + j * 256), 16, 0, 0);
        }
        if (lane < 48) {
            __builtin_amdgcn_global_load_lds(
                (g_u32*)(src + 6 * 256 + lane * 4),
                (lds_u32*)(dst + 6 * 256), 16, 0, 0);
        }
    }
    __syncthreads();   // drains vmcnt (stage) + lgkm (W writes)

    float acc[COUT];
    #pragma unroll
    for (int d = 0; d < COUT; ++d) acc[d] = 0.f;

    const float2* feats2 = reinterpret_cast<const float2*>(feats);
    const int* rowp = s_idx + wv * IPW + lane * K_OFF;

    // ---- scan: per-lane validity bitmap (stride-27 b32, conflict-free) ----
    unsigned bm = 0;
    if (full) {
        #pragma unroll
        for (int k = 0; k < K_OFF; ++k)
            bm |= (rowp[k] >= 0) ? (1u << k) : 0u;
    }

    // wave-max trip count
    int mx = __popc(bm);
    #pragma unroll
    for (int off = 32; off; off >>= 1) mx = max(mx, __shfl_xor(mx, off, 64));

    // ---- batched pair loop: NB gathers clustered via volatile asm ----
    for (int j0 = 0; j0 < mx; j0 += NB) {
        int   kk[NB]; float fm[NB];
        #pragma unroll
        for (int j = 0; j < NB; ++j) {
            const bool alive = (bm != 0);
            kk[j] = alive ? (int)__builtin_ctz(bm) : 0;
            fm[j] = alive ? 1.0f : 0.0f;
            bm &= bm - 1;
        }
        int idx[NB];
        #pragma unroll
        for (int j = 0; j < NB; ++j) idx[j] = rowp[kk[j]];

        // 8 back-to-back global_load_dwordx2 — scheduler cannot reorder volatile asm
        float2 f[NB];
        #pragma unroll
        for (int j = 0; j < NB; ++j) {
            const float2* ap = feats2 + ((fm[j] > 0.f && idx[j] > 0) ? idx[j] : 0);
            asm volatile("global_load_dwordx2 %0, %1, off"
                         : "=v"(f[j]) : "v"(ap));
        }
        asm volatile("s_waitcnt vmcnt(0)" ::: "memory");
        __builtin_amdgcn_sched_barrier(0);   // rule #18: keep FMAs after the waitcnt

        #pragma unroll
        for (int j = 0; j < NB; ++j) {
            const float fx = f[j].x * fm[j], fy = f[j].y * fm[j];
            const int k = kk[j];
            #pragma unroll
            for (int q = 0; q < 4; ++q) {
                const float4 wa = s_w[q * K_OFF + k];        // cin=0
                const float4 wb = s_w[(q + 4) * K_OFF + k];  // cin=1
                acc[q*4+0] = fmaf(fy, wb.x, fmaf(fx, wa.x, acc[q*4+0]));
                acc[q*4+1] = fmaf(fy, wb.y, fmaf(fx, wa.y, acc[q*4+1]));
                acc[q*4+2] = fmaf(fy, wb.z, fmaf(fx, wa.z, acc[q*4+2]));
                acc[q*4+3] = fmaf(fy, wb.w, fmaf(fx, wa.w, acc[q*4+3]));
            }
        }
    }

    // ---- partial-tile fallback: dense masked loop, direct global idx reads ----
    if (!full) {
        const bool pv = (p < n_pts);
        for (int k = 0; k < K_OFF; ++k) {
            const int idx = pv ? nbr[(size_t)p * K_OFF + k] : -1;
            const float fm2 = (idx >= 0) ? 1.0f : 0.0f;
            const float2 f = feats2[idx > 0 ? idx : 0];
            const float fx = f.x * fm2, fy = f.y * fm2;
            #pragma unroll
            for (int q = 0; q < 4; ++q) {
                const float4 wa = s_w[q * K_OFF + k];
                const float4 wb = s_w[(q + 4) * K_OFF + k];
                acc[q*4+0] = fmaf(fy, wb.x, fmaf(fx, wa.x, acc[q*4+0]));
                acc[q*4+1] = fmaf(fy, wb.y, fmaf(fx, wa.y, acc[q*4+1]));
                acc[q*4+2] = fmaf(fy, wb.z, fmaf(fx, wa.z, acc[q*4+2]));
                acc[q*4+3] = fmaf(fy, wb.w, fmaf(fx, wa.w, acc[q*4+3]));
            }
        }
    }

    if (p < n_pts) {
        float4* o = reinterpret_cast<float4*>(out + (size_t)p * COUT);
        o[0] = make_float4(acc[0],  acc[1],  acc[2],  acc[3]);
        o[1] = make_float4(acc[4],  acc[5],  acc[6],  acc[7]);
        o[2] = make_float4(acc[8],  acc[9],  acc[10], acc[11]);
        o[3] = make_float4(acc[12], acc[13], acc[14], acc[15]);
    }
}

extern "C" void kernel_launch(void* const* d_in, const int* in_sizes, int n_in,
                              void* d_out, int out_size, void* d_ws, size_t ws_size,
                              hipStream_t stream) {
    const float* feats = (const float*)d_in[0];
    const float* w     = (const float*)d_in[1];
    const int*   nbr   = (const int*)d_in[2];
    float*       out   = (float*)d_out;

    const int n_pts   = in_sizes[0] / CIN;
    const int n_tiles = (n_pts + 63) / 64;
    const int grid    = (n_tiles + WPB - 1) / WPB;

    spconv_kernel<<<grid, BLK, 0, stream>>>(feats, w, nbr, out, n_pts);
}